// Round 1
// baseline (1204.578 us; speedup 1.0000x reference)
//
#include <hip/hip_runtime.h>
#include <math.h>

#define PDIM 1024
#define EDIM 1024
#define NHEADS 16
#define HDHEAD 64

// ---------------------------------------------------------------------------
// GEMM: C = A(2048x1024) @ W(1024x1024) + bias, optional relu.
// permuted=1 stores head-major: C[((b*16+h)*1024 + i)*64 + d] where
//   row = b*1024+i, col n -> d = n>>4, h = n&15   (head-LAST reshape)
// Tile 64x64, BK=16, 256 threads, 4x4 micro-tile.
// ---------------------------------------------------------------------------
__global__ __launch_bounds__(256) void gemm_bias(
    const float* __restrict__ A, const float* __restrict__ W,
    const float* __restrict__ bias, float* __restrict__ C,
    int permuted, int relu)
{
  const int K = 1024, N = 1024;
  __shared__ float As[16][68];   // [k][m], padded
  __shared__ float Ws[16][64];   // [k][n]
  const int tid = threadIdx.x;
  const int tx = tid & 15;
  const int ty = tid >> 4;
  const int bm = blockIdx.x * 64;
  const int bn = blockIdx.y * 64;

  const int lm = tid >> 2;          // 0..63 row of A tile
  const int lk = (tid & 3) * 4;     // 0,4,8,12
  const int wk = tid >> 4;          // 0..15 row of W tile
  const int wn = (tid & 15) * 4;    // 0..60

  const float* Aptr = A + (size_t)(bm + lm) * K + lk;
  const float* Wptr = W + (size_t)wk * N + bn + wn;

  float acc[4][4];
  #pragma unroll
  for (int i = 0; i < 4; ++i)
    #pragma unroll
    for (int j = 0; j < 4; ++j) acc[i][j] = 0.f;

  for (int k0 = 0; k0 < K; k0 += 16) {
    float4 av = *(const float4*)Aptr; Aptr += 16;
    float4 wv = *(const float4*)Wptr; Wptr += (size_t)16 * N;
    __syncthreads();
    As[lk+0][lm] = av.x; As[lk+1][lm] = av.y;
    As[lk+2][lm] = av.z; As[lk+3][lm] = av.w;
    *(float4*)&Ws[wk][wn] = wv;
    __syncthreads();
    #pragma unroll
    for (int k = 0; k < 16; ++k) {
      float4 a4 = *(const float4*)&As[k][ty*4];
      float4 b4 = *(const float4*)&Ws[k][tx*4];
      float aa[4] = {a4.x, a4.y, a4.z, a4.w};
      float bb[4] = {b4.x, b4.y, b4.z, b4.w};
      #pragma unroll
      for (int i = 0; i < 4; ++i)
        #pragma unroll
        for (int j = 0; j < 4; ++j)
          acc[i][j] = fmaf(aa[i], bb[j], acc[i][j]);
    }
  }

  float4 bia = *(const float4*)(bias + bn + tx*4);
  float bv[4] = {bia.x, bia.y, bia.z, bia.w};
  #pragma unroll
  for (int i = 0; i < 4; ++i) {
    int row = bm + ty*4 + i;
    float v[4];
    #pragma unroll
    for (int j = 0; j < 4; ++j) {
      v[j] = acc[i][j] + bv[j];
      if (relu) v[j] = fmaxf(v[j], 0.f);
    }
    if (!permuted) {
      float4 o4 = {v[0], v[1], v[2], v[3]};
      *(float4*)(C + (size_t)row * N + bn + tx*4) = o4;
    } else {
      int bb_ = row >> 10;         // batch
      int ii  = row & 1023;        // position
      #pragma unroll
      for (int j = 0; j < 4; ++j) {
        int n = bn + tx*4 + j;
        int d = n >> 4;
        int hh = n & 15;
        C[(((size_t)(bb_ * NHEADS + hh)) * PDIM + ii) * HDHEAD + d] = v[j];
      }
    }
  }
}

// ---------------------------------------------------------------------------
// Attention for head-major q/k/v: (B, NH, 1024, 64).
// Block = (i-tile of 64, head, batch). Two passes over 16 j-tiles of 64.
// softmax over j, then p += mask (mask added AFTER softmax, as in reference),
// out[b, i, o*16 + h] = sum_j p * v.
// ---------------------------------------------------------------------------
__global__ __launch_bounds__(256) void attn_kernel(
    const float* __restrict__ qh, const float* __restrict__ kh,
    const float* __restrict__ vh,
    const float* __restrict__ mask1, const float* __restrict__ mask2,
    float* __restrict__ out)
{
  __shared__ float qsT[64][68];  // [d][i]
  __shared__ float ksT[64][68];  // [d][j]
  __shared__ float vs [64][68];  // [j][o]
  __shared__ float psT[64][68];  // [j][i]  (aliased as reduce scratch)
  __shared__ float mrow[64];
  __shared__ float lrow[64];     // holds 1/l

  const int tid = threadIdx.x;
  const int i0  = blockIdx.x * 64;
  const int h   = blockIdx.y;
  const int b   = blockIdx.z;

  const size_t bhoff = ((size_t)b * NHEADS + h) * PDIM * HDHEAD;
  const float* qbase = qh + bhoff + (size_t)i0 * HDHEAD;
  const float* kbase = kh + bhoff;
  const float* vbase = vh + bhoff;

  // stage q transposed: qsT[d][i]
  #pragma unroll
  for (int r = 0; r < 4; ++r) {
    int u = tid + r * 256;       // float4 index 0..1023
    int i = u >> 4;
    int d0 = (u & 15) * 4;
    float4 v = *(const float4*)(qbase + (size_t)i * HDHEAD + d0);
    qsT[d0+0][i] = v.x; qsT[d0+1][i] = v.y;
    qsT[d0+2][i] = v.z; qsT[d0+3][i] = v.w;
  }

  const int ig = tid & 15;   // i micro group (i = ig*4..)
  const int jg = tid >> 4;   // j / o micro group

  float mi[4], li[4];
  #pragma unroll
  for (int ii = 0; ii < 4; ++ii) { mi[ii] = -1e30f; li[ii] = 0.f; }

  // ------------------- pass 1: row max & sumexp -------------------
  for (int jt = 0; jt < 16; ++jt) {
    __syncthreads();
    #pragma unroll
    for (int r = 0; r < 4; ++r) {
      int u = tid + r * 256;
      int j = u >> 4;
      int d0 = (u & 15) * 4;
      float4 v = *(const float4*)(kbase + (size_t)(jt*64 + j) * HDHEAD + d0);
      ksT[d0+0][j] = v.x; ksT[d0+1][j] = v.y;
      ksT[d0+2][j] = v.z; ksT[d0+3][j] = v.w;
    }
    __syncthreads();

    float s[4][4];
    #pragma unroll
    for (int ii = 0; ii < 4; ++ii)
      #pragma unroll
      for (int jj = 0; jj < 4; ++jj) s[ii][jj] = 0.f;

    #pragma unroll 8
    for (int d = 0; d < 64; ++d) {
      float4 q4 = *(const float4*)&qsT[d][ig*4];
      float4 k4 = *(const float4*)&ksT[d][jg*4];
      float qa[4] = {q4.x, q4.y, q4.z, q4.w};
      float ka[4] = {k4.x, k4.y, k4.z, k4.w};
      #pragma unroll
      for (int ii = 0; ii < 4; ++ii)
        #pragma unroll
        for (int jj = 0; jj < 4; ++jj)
          s[ii][jj] = fmaf(qa[ii], ka[jj], s[ii][jj]);
    }

    #pragma unroll
    for (int ii = 0; ii < 4; ++ii) {
      float sc[4];
      #pragma unroll
      for (int jj = 0; jj < 4; ++jj) sc[jj] = s[ii][jj] * 0.125f;
      float tmax = fmaxf(fmaxf(sc[0], sc[1]), fmaxf(sc[2], sc[3]));
      float nm = fmaxf(mi[ii], tmax);
      float add = __expf(sc[0]-nm) + __expf(sc[1]-nm)
                + __expf(sc[2]-nm) + __expf(sc[3]-nm);
      li[ii] = li[ii] * __expf(mi[ii] - nm) + add;
      mi[ii] = nm;
    }
  }

  // reduce (m,l) across the 16 jg-threads per row (scratch aliased in psT)
  float* red = &psT[0][0];
  __syncthreads();
  #pragma unroll
  for (int ii = 0; ii < 4; ++ii) {
    int i = ig*4 + ii;
    red[i*32 + jg]      = mi[ii];
    red[i*32 + 16 + jg] = li[ii];
  }
  __syncthreads();
  if (tid < 64) {
    float m = -1e30f;
    #pragma unroll
    for (int t = 0; t < 16; ++t) m = fmaxf(m, red[tid*32 + t]);
    float l = 0.f;
    #pragma unroll
    for (int t = 0; t < 16; ++t) l += red[tid*32 + 16 + t] * __expf(red[tid*32 + t] - m);
    mrow[tid] = m;
    lrow[tid] = 1.f / l;
  }

  // ------------------- pass 2: p = softmax + mask; out = p @ v -----
  const int og = jg;
  float ao[4][4];
  #pragma unroll
  for (int ii = 0; ii < 4; ++ii)
    #pragma unroll
    for (int oo = 0; oo < 4; ++oo) ao[ii][oo] = 0.f;

  const float* m1b = mask1 ? (mask1 + ((size_t)b * PDIM + i0) * 1024) : nullptr;
  const float* m2b = mask2 ? (mask2 + ((size_t)b * PDIM + i0) * 1024) : nullptr;

  for (int jt = 0; jt < 16; ++jt) {
    __syncthreads();
    #pragma unroll
    for (int r = 0; r < 4; ++r) {
      int u = tid + r * 256;
      int j = u >> 4;
      int d0 = (u & 15) * 4;
      float4 kv = *(const float4*)(kbase + (size_t)(jt*64 + j) * HDHEAD + d0);
      ksT[d0+0][j] = kv.x; ksT[d0+1][j] = kv.y;
      ksT[d0+2][j] = kv.z; ksT[d0+3][j] = kv.w;
      float4 vv = *(const float4*)(vbase + (size_t)(jt*64 + j) * HDHEAD + d0);
      *(float4*)&vs[j][d0] = vv;
    }
    __syncthreads();

    float s[4][4];
    #pragma unroll
    for (int ii = 0; ii < 4; ++ii)
      #pragma unroll
      for (int jj = 0; jj < 4; ++jj) s[ii][jj] = 0.f;

    #pragma unroll 8
    for (int d = 0; d < 64; ++d) {
      float4 q4 = *(const float4*)&qsT[d][ig*4];
      float4 k4 = *(const float4*)&ksT[d][jg*4];
      float qa[4] = {q4.x, q4.y, q4.z, q4.w};
      float ka[4] = {k4.x, k4.y, k4.z, k4.w};
      #pragma unroll
      for (int ii = 0; ii < 4; ++ii)
        #pragma unroll
        for (int jj = 0; jj < 4; ++jj)
          s[ii][jj] = fmaf(qa[ii], ka[jj], s[ii][jj]);
    }

    #pragma unroll
    for (int jj = 0; jj < 4; ++jj) {
      int jl = jg*4 + jj;
      int jglob = jt*64 + jl;
      float pv[4];
      #pragma unroll
      for (int ii = 0; ii < 4; ++ii) {
        int i = ig*4 + ii;
        float p = __expf(s[ii][jj] * 0.125f - mrow[i]) * lrow[i];
        if (m1b) p += m1b[(size_t)i * 1024 + jglob];
        if (m2b) p += m2b[(size_t)i * 1024 + jglob];
        pv[ii] = p;
      }
      float4 p4 = {pv[0], pv[1], pv[2], pv[3]};
      *(float4*)&psT[jl][ig*4] = p4;
    }
    __syncthreads();

    #pragma unroll 8
    for (int j = 0; j < 64; ++j) {
      float4 p4 = *(const float4*)&psT[j][ig*4];
      float4 v4 = *(const float4*)&vs[j][og*4];
      float pa[4] = {p4.x, p4.y, p4.z, p4.w};
      float va[4] = {v4.x, v4.y, v4.z, v4.w};
      #pragma unroll
      for (int ii = 0; ii < 4; ++ii)
        #pragma unroll
        for (int oo = 0; oo < 4; ++oo)
          ao[ii][oo] = fmaf(pa[ii], va[oo], ao[ii][oo]);
    }
  }

  #pragma unroll
  for (int ii = 0; ii < 4; ++ii) {
    int i = ig*4 + ii;
    #pragma unroll
    for (int oo = 0; oo < 4; ++oo) {
      int o = og*4 + oo;
      out[((size_t)b * PDIM + i0 + i) * EDIM + o * NHEADS + h] = ao[ii][oo];
    }
  }
}

// ---------------------------------------------------------------------------
// y = LayerNorm(x)*g + beta + res   (row = 1024 floats, block per row)
// ---------------------------------------------------------------------------
__global__ __launch_bounds__(256) void ln_res_kernel(
    const float* __restrict__ x, const float* __restrict__ res,
    const float* __restrict__ g, const float* __restrict__ beta,
    float* __restrict__ out)
{
  const int row = blockIdx.x;
  const int tid = threadIdx.x;
  const float* xr = x + (size_t)row * EDIM;
  float4 v = *(const float4*)(xr + tid*4);
  float s  = v.x + v.y + v.z + v.w;
  float sq = v.x*v.x + v.y*v.y + v.z*v.z + v.w*v.w;
  #pragma unroll
  for (int off = 32; off > 0; off >>= 1) {
    s  += __shfl_down(s,  off, 64);
    sq += __shfl_down(sq, off, 64);
  }
  __shared__ float rs[4], rq[4], stat[2];
  int wave = tid >> 6, lane = tid & 63;
  if (lane == 0) { rs[wave] = s; rq[wave] = sq; }
  __syncthreads();
  if (tid == 0) {
    float S = rs[0] + rs[1] + rs[2] + rs[3];
    float Q = rq[0] + rq[1] + rq[2] + rq[3];
    float mean = S * (1.f/1024.f);
    float var  = Q * (1.f/1024.f) - mean*mean;
    stat[0] = mean;
    stat[1] = rsqrtf(var + 1e-5f);
  }
  __syncthreads();
  float mean = stat[0], rstd = stat[1];
  float4 g4 = *(const float4*)(g + tid*4);
  float4 b4 = *(const float4*)(beta + tid*4);
  float4 r4 = *(const float4*)(res + (size_t)row * EDIM + tid*4);
  float4 o4;
  o4.x = (v.x - mean) * rstd * g4.x + b4.x + r4.x;
  o4.y = (v.y - mean) * rstd * g4.y + b4.y + r4.y;
  o4.z = (v.z - mean) * rstd * g4.z + b4.z + r4.z;
  o4.w = (v.w - mean) * rstd * g4.w + b4.w + r4.w;
  *(float4*)(out + (size_t)row * EDIM + tid*4) = o4;
}

// ---------------------------------------------------------------------------
extern "C" void kernel_launch(void* const* d_in, const int* in_sizes, int n_in,
                              void* d_out, int out_size, void* d_ws, size_t ws_size,
                              hipStream_t stream) {
  const float* x    = (const float*)d_in[0];
  const float* ctx  = (const float*)d_in[1];
  const float* cm   = (const float*)d_in[2];   // causal_mask
  const float* ppm  = (const float*)d_in[3];   // problem_pad_mask
  const float* cpm  = (const float*)d_in[4];   // context_pad_mask
  const float* saWq = (const float*)d_in[5];
  const float* sabq = (const float*)d_in[6];
  const float* saWk = (const float*)d_in[7];
  const float* sabk = (const float*)d_in[8];
  const float* saWv = (const float*)d_in[9];
  const float* sabv = (const float*)d_in[10];
  const float* caWq = (const float*)d_in[11];
  const float* cabq = (const float*)d_in[12];
  const float* caWk = (const float*)d_in[13];
  const float* cabk = (const float*)d_in[14];
  const float* caWv = (const float*)d_in[15];
  const float* cabv = (const float*)d_in[16];
  const float* ln1g = (const float*)d_in[17];
  const float* ln1b = (const float*)d_in[18];
  const float* ln2g = (const float*)d_in[19];
  const float* ln2b = (const float*)d_in[20];
  const float* ln3g = (const float*)d_in[21];
  const float* ln3b = (const float*)d_in[22];
  const float* W1   = (const float*)d_in[23];
  const float* b1   = (const float*)d_in[24];
  const float* W2   = (const float*)d_in[25];
  const float* b2   = (const float*)d_in[26];

  float* ws = (float*)d_ws;
  const size_t SLOT = (size_t)2 * 1024 * 1024;  // 2M floats = 8MB
  float* S0 = ws + 0*SLOT;   // qh (head-major)
  float* S1 = ws + 1*SLOT;   // kh
  float* S2 = ws + 2*SLOT;   // vh
  float* S3 = ws + 3*SLOT;   // attn out (flat head-last)
  float* S4 = ws + 4*SLOT;   // x1
  float* S5 = ws + 5*SLOT;   // x2
  float* outp = (float*)d_out;

  dim3 gg(32, 16);           // 2048/64 x 1024/64
  dim3 ag(16, NHEADS, 2);    // i-tiles x heads x batch
  dim3 lg(2048);

  // ---- self attention ----
  gemm_bias<<<gg, 256, 0, stream>>>(x, saWq, sabq, S0, 1, 0);
  gemm_bias<<<gg, 256, 0, stream>>>(x, saWk, sabk, S1, 1, 0);
  gemm_bias<<<gg, 256, 0, stream>>>(x, saWv, sabv, S2, 1, 0);
  attn_kernel<<<ag, 256, 0, stream>>>(S0, S1, S2, cm, ppm, S3);
  ln_res_kernel<<<lg, 256, 0, stream>>>(S3, x, ln1g, ln1b, S4);

  // ---- cross attention ----
  gemm_bias<<<gg, 256, 0, stream>>>(S4,  caWq, cabq, S0, 1, 0);
  gemm_bias<<<gg, 256, 0, stream>>>(ctx, caWk, cabk, S1, 1, 0);
  gemm_bias<<<gg, 256, 0, stream>>>(ctx, caWv, cabv, S2, 1, 0);
  attn_kernel<<<ag, 256, 0, stream>>>(S0, S1, S2, cpm, nullptr, S3);
  ln_res_kernel<<<lg, 256, 0, stream>>>(S3, S4, ln2g, ln2b, S5);

  // ---- MLP ----
  gemm_bias<<<gg, 256, 0, stream>>>(S5, W1, b1, S0, 0, 1);   // relu
  gemm_bias<<<gg, 256, 0, stream>>>(S0, W2, b2, S1, 0, 0);
  ln_res_kernel<<<lg, 256, 0, stream>>>(S1, S5, ln3g, ln3b, outp);
}

// Round 2
// 483.029 us; speedup vs baseline: 2.4938x; 2.4938x over previous
//
#include <hip/hip_runtime.h>
#include <math.h>

#define NHEADS 16

typedef __attribute__((ext_vector_type(8))) short bf16x8;
typedef __attribute__((ext_vector_type(4))) float f32x4;

__device__ inline short f2b(float f) {
  unsigned u = __float_as_uint(f);
  u += 0x7fffu + ((u >> 16) & 1u);   // round-to-nearest-even
  return (short)(u >> 16);
}
__device__ inline float b2f(short s) {
  return __uint_as_float(((unsigned)(unsigned short)s) << 16);
}
__device__ inline void gld16(const void* g, void* l) {
  __builtin_amdgcn_global_load_lds(
      (const __attribute__((address_space(1))) unsigned int*)g,
      (__attribute__((address_space(3))) unsigned int*)l, 16, 0, 0);
}
#define MFMA16(a, b, c) __builtin_amdgcn_mfma_f32_16x16x32_bf16(a, b, c, 0, 0, 0)

// ---------------------------------------------------------------------------
// fp32 -> bf16 row convert (grid-stride over float4)
// ---------------------------------------------------------------------------
__global__ __launch_bounds__(256) void cvtb(const float* __restrict__ in,
                                            short* __restrict__ out, int n4) {
  int i = blockIdx.x * 256 + threadIdx.x;
  if (i < n4) {
    float4 v = ((const float4*)in)[i];
    short4 s;
    s.x = f2b(v.x); s.y = f2b(v.y); s.z = f2b(v.z); s.w = f2b(v.w);
    ((short4*)out)[i] = s;
  }
}

// combined mask: out_bf16 = bf16(a + (b?b:0))
__global__ __launch_bounds__(256) void maskcomb(const float* __restrict__ a,
                                                const float* __restrict__ b,
                                                short* __restrict__ out, int n4) {
  int i = blockIdx.x * 256 + threadIdx.x;
  if (i < n4) {
    float4 va = ((const float4*)a)[i];
    if (b) {
      float4 vb = ((const float4*)b)[i];
      va.x += vb.x; va.y += vb.y; va.z += vb.z; va.w += vb.w;
    }
    short4 s;
    s.x = f2b(va.x); s.y = f2b(va.y); s.z = f2b(va.z); s.w = f2b(va.w);
    ((short4*)out)[i] = s;
  }
}

// ---------------------------------------------------------------------------
// Weight transpose+convert: W fp32 [1024 k][1024 n] -> bf16 [n][k].
// grid (16 n-tiles, 16 k-tiles, 8 weights), 256 threads, 64x64 LDS tile.
// ---------------------------------------------------------------------------
__global__ __launch_bounds__(256) void wtrans(
    const float* W0, const float* W1, const float* W2, const float* W3,
    const float* W4, const float* W5, const float* W6, const float* W7,
    short* __restrict__ out) {
  __shared__ float t[64][65];
  const float* W;
  switch (blockIdx.z) {
    case 0: W = W0; break; case 1: W = W1; break;
    case 2: W = W2; break; case 3: W = W3; break;
    case 4: W = W4; break; case 5: W = W5; break;
    case 6: W = W6; break; default: W = W7; break;
  }
  short* o = out + (size_t)blockIdx.z * 1024 * 1024;
  const int tid = threadIdx.x;
  const int n0 = blockIdx.x * 64, k0 = blockIdx.y * 64;
  const int cg = (tid & 15) * 4, rg = tid >> 4;
  #pragma unroll
  for (int r = 0; r < 4; ++r) {
    int kl = rg + r * 16;
    float4 v = *(const float4*)(W + (size_t)(k0 + kl) * 1024 + n0 + cg);
    t[kl][cg + 0] = v.x; t[kl][cg + 1] = v.y;
    t[kl][cg + 2] = v.z; t[kl][cg + 3] = v.w;
  }
  __syncthreads();
  #pragma unroll
  for (int r = 0; r < 4; ++r) {
    int nl = rg + r * 16;
    short4 s;
    s.x = f2b(t[cg + 0][nl]); s.y = f2b(t[cg + 1][nl]);
    s.z = f2b(t[cg + 2][nl]); s.w = f2b(t[cg + 3][nl]);
    *(short4*)(o + (size_t)(n0 + nl) * 1024 + k0 + cg) = s;
  }
}

// ---------------------------------------------------------------------------
// bf16 MFMA GEMM: C = A(2048x1024) @ Bt^T + bias. Bt is [n][k] bf16.
// Tile 128m x 64n, BK=32, 256 threads; wave computes 32m x 64n (2x4 frags).
// mode: 0 = fp32 [m][n], 1 = bf16 [m][n], 2 = bf16 head-major
//       out[((b*16+h)*1024+i)*64+d], d=n>>4, h=n&15.
// ---------------------------------------------------------------------------
__global__ __launch_bounds__(256) void gemm_bf16(
    const short* __restrict__ A, const short* __restrict__ Bt,
    const float* __restrict__ bias, void* __restrict__ C,
    int mode, int relu) {
  __shared__ short As[128 * 32];   // [m][k]
  __shared__ short Bs[64 * 32];    // [n][k]
  const int tid = threadIdx.x;
  const int w = tid >> 6, l = tid & 63;
  const int ln = l & 15, lq = l >> 4;
  const int m0 = blockIdx.x * 128;
  const int n0 = blockIdx.y * 64;
  const int K = 1024;

  f32x4 acc[2][4];
  #pragma unroll
  for (int s = 0; s < 2; ++s)
    #pragma unroll
    for (int t = 0; t < 4; ++t) acc[s][t] = (f32x4){0.f, 0.f, 0.f, 0.f};

  const short* ga0 = A + (size_t)(m0 + w * 32 + (l >> 2)) * K + (l & 3) * 8;
  const short* ga1 = ga0 + (size_t)16 * K;
  const short* gb  = Bt + (size_t)(n0 + w * 16 + (l >> 2)) * K + (l & 3) * 8;
  short* la0 = &As[w * 1024];
  short* la1 = &As[w * 1024 + 512];
  short* lb  = &Bs[w * 512];

  float bv[4];
  #pragma unroll
  for (int t = 0; t < 4; ++t) bv[t] = bias[n0 + t * 16 + ln];

  for (int k0 = 0; k0 < K; k0 += 32) {
    __syncthreads();
    gld16(ga0 + k0, la0);
    gld16(ga1 + k0, la1);
    gld16(gb + k0, lb);
    __syncthreads();
    bf16x8 af[2], bfr[4];
    af[0] = *(const bf16x8*)&As[(w * 32 + ln) * 32 + lq * 8];
    af[1] = *(const bf16x8*)&As[(w * 32 + 16 + ln) * 32 + lq * 8];
    #pragma unroll
    for (int t = 0; t < 4; ++t)
      bfr[t] = *(const bf16x8*)&Bs[(t * 16 + ln) * 32 + lq * 8];
    #pragma unroll
    for (int s = 0; s < 2; ++s)
      #pragma unroll
      for (int t = 0; t < 4; ++t)
        acc[s][t] = MFMA16(af[s], bfr[t], acc[s][t]);
  }

  #pragma unroll
  for (int s = 0; s < 2; ++s) {
    #pragma unroll
    for (int t = 0; t < 4; ++t) {
      #pragma unroll
      for (int r = 0; r < 4; ++r) {
        int m = m0 + w * 32 + s * 16 + lq * 4 + r;
        int n = n0 + t * 16 + ln;
        float v = acc[s][t][r] + bv[t];
        if (relu) v = fmaxf(v, 0.f);
        if (mode == 0) {
          ((float*)C)[(size_t)m * 1024 + n] = v;
        } else if (mode == 1) {
          ((short*)C)[(size_t)m * 1024 + n] = f2b(v);
        } else {
          int bb = m >> 10, ii = m & 1023;
          int d = n >> 4, hh = n & 15;
          ((short*)C)[(((size_t)(bb * NHEADS + hh)) * 1024 + ii) * 64 + d] = f2b(v);
        }
      }
    }
  }
}

// ---------------------------------------------------------------------------
// MFMA attention. q/k/v bf16 head-major (B,NH,1024,64); maskb bf16 combined
// (B,1024,1024) added AFTER softmax; out fp32 (B,1024,1024), col = o*16+h.
// grid (16 i-tiles, 16 heads, 2 batch), 256 threads (4 waves).
// Pass 1: waves split j (online m,l). Pass 2: recompute S, P->LDS, PV MFMA
// with waves splitting o. V transposed in LDS for the B operand.
// ---------------------------------------------------------------------------
__global__ __launch_bounds__(256) void attn_mfma(
    const short* __restrict__ qh, const short* __restrict__ kh,
    const short* __restrict__ vh, const short* __restrict__ maskb,
    float* __restrict__ out) {
  __shared__ short Ks[64 * 64];    // [j][d] unpadded (global_load_lds)
  __shared__ short Vt[64 * 72];    // [o][j] padded
  __shared__ short Ps[64 * 72];    // [i][j] padded
  __shared__ float mred[4 * 64], lred[4 * 64];
  __shared__ float sfin[128];      // [0:64) m, [64:128) 1/l

  const int tid = threadIdx.x;
  const int w = tid >> 6, l = tid & 63;
  const int ln = l & 15, lq = l >> 4;
  const int i0 = blockIdx.x * 64;
  const int h = blockIdx.y;
  const int b = blockIdx.z;
  const size_t bh = ((size_t)(b * NHEADS + h)) * 1024 * 64;

  // Q fragments in registers: q[msub][kchunk]
  bf16x8 qf[4][2];
  #pragma unroll
  for (int ms = 0; ms < 4; ++ms)
    #pragma unroll
    for (int kc = 0; kc < 2; ++kc)
      qf[ms][kc] = *(const bf16x8*)(qh + bh +
          (size_t)(i0 + ms * 16 + ln) * 64 + kc * 32 + lq * 8);

  const short* gk0 = kh + bh + (size_t)(w * 16 + (l >> 3)) * 64 + (l & 7) * 8;
  const short* gk1 = gk0 + (size_t)8 * 64;
  short* lk0 = &Ks[w * 1024];
  short* lk1 = &Ks[w * 1024 + 512];

  float mrun[16], lrun[16];
  #pragma unroll
  for (int i = 0; i < 16; ++i) { mrun[i] = -1e30f; lrun[i] = 0.f; }

  // ---------------- pass 1: online (m,l); wave w owns j-sub w --------------
  for (int jt = 0; jt < 16; ++jt) {
    __syncthreads();
    gld16(gk0 + (size_t)jt * 4096, lk0);
    gld16(gk1 + (size_t)jt * 4096, lk1);
    __syncthreads();
    bf16x8 kb0 = *(const bf16x8*)&Ks[(w * 16 + ln) * 64 + lq * 8];
    bf16x8 kb1 = *(const bf16x8*)&Ks[(w * 16 + ln) * 64 + 32 + lq * 8];
    #pragma unroll
    for (int ms = 0; ms < 4; ++ms) {
      f32x4 s = (f32x4){0.f, 0.f, 0.f, 0.f};
      s = MFMA16(qf[ms][0], kb0, s);
      s = MFMA16(qf[ms][1], kb1, s);
      #pragma unroll
      for (int r = 0; r < 4; ++r) {
        float val = s[r] * 0.125f;
        int idx = ms * 4 + r;
        float nm = fmaxf(mrun[idx], val);
        lrun[idx] = lrun[idx] * __expf(mrun[idx] - nm) + __expf(val - nm);
        mrun[idx] = nm;
      }
    }
  }

  // butterfly merge across the 16 j-columns held by ln=0..15
  #pragma unroll
  for (int off = 1; off < 16; off <<= 1) {
    #pragma unroll
    for (int idx = 0; idx < 16; ++idx) {
      float mo = __shfl_xor(mrun[idx], off, 64);
      float lo = __shfl_xor(lrun[idx], off, 64);
      float nm = fmaxf(mrun[idx], mo);
      lrun[idx] = lrun[idx] * __expf(mrun[idx] - nm) + lo * __expf(mo - nm);
      mrun[idx] = nm;
    }
  }
  if (ln == 0) {
    #pragma unroll
    for (int idx = 0; idx < 16; ++idx) {
      int row = (idx >> 2) * 16 + lq * 4 + (idx & 3);
      mred[w * 64 + row] = mrun[idx];
      lred[w * 64 + row] = lrun[idx];
    }
  }
  __syncthreads();
  if (tid < 64) {
    float m = -1e30f;
    #pragma unroll
    for (int ww = 0; ww < 4; ++ww) m = fmaxf(m, mred[ww * 64 + tid]);
    float ls = 0.f;
    #pragma unroll
    for (int ww = 0; ww < 4; ++ww)
      ls += lred[ww * 64 + tid] * __expf(mred[ww * 64 + tid] - m);
    sfin[tid] = m;
    sfin[64 + tid] = 1.f / ls;
  }
  __syncthreads();
  float mv[16], iv[16];
  #pragma unroll
  for (int idx = 0; idx < 16; ++idx) {
    int row = (idx >> 2) * 16 + lq * 4 + (idx & 3);
    mv[idx] = sfin[row];
    iv[idx] = sfin[64 + row];
  }

  // ---------------- pass 2: P = softmax + mask; O += P @ V ----------------
  f32x4 oacc[4];
  #pragma unroll
  for (int ms = 0; ms < 4; ++ms) oacc[ms] = (f32x4){0.f, 0.f, 0.f, 0.f};

  const short* gv = vh + bh + (size_t)(tid >> 2) * 64 + (tid & 3) * 16;
  const int jl_v = tid >> 2, o0_v = (tid & 3) * 16;

  for (int jt = 0; jt < 16; ++jt) {
    __syncthreads();
    gld16(gk0 + (size_t)jt * 4096, lk0);
    gld16(gk1 + (size_t)jt * 4096, lk1);
    bf16x8 v0 = *(const bf16x8*)(gv + (size_t)jt * 4096);
    bf16x8 v1 = *(const bf16x8*)(gv + (size_t)jt * 4096 + 8);
    #pragma unroll
    for (int e = 0; e < 8; ++e) Vt[(o0_v + e) * 72 + jl_v] = v0[e];
    #pragma unroll
    for (int e = 0; e < 8; ++e) Vt[(o0_v + 8 + e) * 72 + jl_v] = v1[e];
    // masks for this tile (col = jt*64 + w*16 + ln)
    float mk[16];
    #pragma unroll
    for (int idx = 0; idx < 16; ++idx) {
      int row = (idx >> 2) * 16 + lq * 4 + (idx & 3);
      mk[idx] = b2f(maskb[((size_t)(b * 1024) + i0 + row) * 1024 +
                          jt * 64 + w * 16 + ln]);
    }
    __syncthreads();
    bf16x8 kb0 = *(const bf16x8*)&Ks[(w * 16 + ln) * 64 + lq * 8];
    bf16x8 kb1 = *(const bf16x8*)&Ks[(w * 16 + ln) * 64 + 32 + lq * 8];
    #pragma unroll
    for (int ms = 0; ms < 4; ++ms) {
      f32x4 s = (f32x4){0.f, 0.f, 0.f, 0.f};
      s = MFMA16(qf[ms][0], kb0, s);
      s = MFMA16(qf[ms][1], kb1, s);
      #pragma unroll
      for (int r = 0; r < 4; ++r) {
        int idx = ms * 4 + r;
        float p = __expf(s[r] * 0.125f - mv[idx]) * iv[idx] + mk[idx];
        int row = ms * 16 + lq * 4 + r;
        Ps[row * 72 + w * 16 + ln] = f2b(p);
      }
    }
    __syncthreads();
    bf16x8 vb0 = *(const bf16x8*)&Vt[(w * 16 + ln) * 72 + lq * 8];
    bf16x8 vb1 = *(const bf16x8*)&Vt[(w * 16 + ln) * 72 + 32 + lq * 8];
    #pragma unroll
    for (int ms = 0; ms < 4; ++ms) {
      bf16x8 pa0 = *(const bf16x8*)&Ps[(ms * 16 + ln) * 72 + lq * 8];
      bf16x8 pa1 = *(const bf16x8*)&Ps[(ms * 16 + ln) * 72 + 32 + lq * 8];
      oacc[ms] = MFMA16(pa0, vb0, oacc[ms]);
      oacc[ms] = MFMA16(pa1, vb1, oacc[ms]);
    }
  }

  #pragma unroll
  for (int ms = 0; ms < 4; ++ms) {
    #pragma unroll
    for (int r = 0; r < 4; ++r) {
      int row = i0 + ms * 16 + lq * 4 + r;
      int col = (w * 16 + ln) * NHEADS + h;
      out[((size_t)b * 1024 + row) * 1024 + col] = oacc[ms][r];
    }
  }
}

// ---------------------------------------------------------------------------
// LayerNorm(x_fp32)*g + beta + res_bf16 -> fp32 or bf16
// ---------------------------------------------------------------------------
__global__ __launch_bounds__(256) void ln_kernel(
    const float* __restrict__ x, const short* __restrict__ res,
    const float* __restrict__ g, const float* __restrict__ be,
    void* __restrict__ outp, int out_bf16) {
  const int row = blockIdx.x;
  const int tid = threadIdx.x;
  float4 v = ((const float4*)(x + (size_t)row * 1024))[tid];
  float s = v.x + v.y + v.z + v.w;
  float sq = v.x * v.x + v.y * v.y + v.z * v.z + v.w * v.w;
  #pragma unroll
  for (int off = 32; off > 0; off >>= 1) {
    s += __shfl_down(s, off, 64);
    sq += __shfl_down(sq, off, 64);
  }
  __shared__ float rs[4], rq[4], stat[2];
  int wave = tid >> 6, lane = tid & 63;
  if (lane == 0) { rs[wave] = s; rq[wave] = sq; }
  __syncthreads();
  if (tid == 0) {
    float S = rs[0] + rs[1] + rs[2] + rs[3];
    float Q = rq[0] + rq[1] + rq[2] + rq[3];
    float mean = S * (1.f / 1024.f);
    float var = Q * (1.f / 1024.f) - mean * mean;
    stat[0] = mean;
    stat[1] = rsqrtf(var + 1e-5f);
  }
  __syncthreads();
  float mean = stat[0], rstd = stat[1];
  float4 g4 = ((const float4*)g)[tid];
  float4 b4 = ((const float4*)be)[tid];
  short4 r4 = ((const short4*)(res + (size_t)row * 1024))[tid];
  float o0 = (v.x - mean) * rstd * g4.x + b4.x + b2f(r4.x);
  float o1 = (v.y - mean) * rstd * g4.y + b4.y + b2f(r4.y);
  float o2 = (v.z - mean) * rstd * g4.z + b4.z + b2f(r4.z);
  float o3 = (v.w - mean) * rstd * g4.w + b4.w + b2f(r4.w);
  if (out_bf16) {
    short4 o;
    o.x = f2b(o0); o.y = f2b(o1); o.z = f2b(o2); o.w = f2b(o3);
    ((short4*)outp)[(size_t)row * 256 + tid] = o;
  } else {
    float4 o = {o0, o1, o2, o3};
    ((float4*)outp)[(size_t)row * 256 + tid] = o;
  }
}

// ---------------------------------------------------------------------------
extern "C" void kernel_launch(void* const* d_in, const int* in_sizes, int n_in,
                              void* d_out, int out_size, void* d_ws, size_t ws_size,
                              hipStream_t stream) {
  const float* x    = (const float*)d_in[0];
  const float* ctx  = (const float*)d_in[1];
  const float* cm   = (const float*)d_in[2];
  const float* ppm  = (const float*)d_in[3];
  const float* cpm  = (const float*)d_in[4];
  const float* saWq = (const float*)d_in[5];
  const float* sabq = (const float*)d_in[6];
  const float* saWk = (const float*)d_in[7];
  const float* sabk = (const float*)d_in[8];
  const float* saWv = (const float*)d_in[9];
  const float* sabv = (const float*)d_in[10];
  const float* caWq = (const float*)d_in[11];
  const float* cabq = (const float*)d_in[12];
  const float* caWk = (const float*)d_in[13];
  const float* cabk = (const float*)d_in[14];
  const float* caWv = (const float*)d_in[15];
  const float* cabv = (const float*)d_in[16];
  const float* ln1g = (const float*)d_in[17];
  const float* ln1b = (const float*)d_in[18];
  const float* ln2g = (const float*)d_in[19];
  const float* ln2b = (const float*)d_in[20];
  const float* ln3g = (const float*)d_in[21];
  const float* ln3b = (const float*)d_in[22];
  const float* W1   = (const float*)d_in[23];
  const float* b1   = (const float*)d_in[24];
  const float* W2   = (const float*)d_in[25];
  const float* b2   = (const float*)d_in[26];

  char* ws = (char*)d_ws;
  const size_t MB = 1024 * 1024;
  short* WT   = (short*)(ws);              // 8 x 2MB bf16 [n][k]
  short* MBSA = (short*)(ws + 16 * MB);
  short* MBCA = (short*)(ws + 20 * MB);
  short* XB   = (short*)(ws + 24 * MB);
  short* CTXB = (short*)(ws + 28 * MB);
  short* QH   = (short*)(ws + 32 * MB);    // also HB for MLP
  short* KH   = (short*)(ws + 36 * MB);
  short* VH   = (short*)(ws + 40 * MB);
  float* S3   = (float*)(ws + 44 * MB);    // fp32 8MB
  short* X1B  = (short*)(ws + 52 * MB);
  short* X2B  = (short*)(ws + 56 * MB);
  float* outp = (float*)d_out;

  const int n4 = 2048 * 1024 / 4;
  dim3 cg(n4 / 256);
  dim3 wg(16, 16, 8);
  dim3 gg(16, 16);          // 2048/128 x 1024/64
  dim3 ag(16, NHEADS, 2);
  dim3 lg(2048);

  // prep
  wtrans<<<wg, 256, 0, stream>>>(saWq, saWk, saWv, caWq, caWk, caWv, W1, W2, WT);
  cvtb<<<cg, 256, 0, stream>>>(x, XB, n4);
  cvtb<<<cg, 256, 0, stream>>>(ctx, CTXB, n4);
  maskcomb<<<cg, 256, 0, stream>>>(cm, ppm, MBSA, n4);
  maskcomb<<<cg, 256, 0, stream>>>(cpm, nullptr, MBCA, n4);

  // self attention
  gemm_bf16<<<gg, 256, 0, stream>>>(XB, WT + 0 * MB, sabq, QH, 2, 0);
  gemm_bf16<<<gg, 256, 0, stream>>>(XB, WT + 1 * MB, sabk, KH, 2, 0);
  gemm_bf16<<<gg, 256, 0, stream>>>(XB, WT + 2 * MB, sabv, VH, 2, 0);
  attn_mfma<<<ag, 256, 0, stream>>>(QH, KH, VH, MBSA, S3);
  ln_kernel<<<lg, 256, 0, stream>>>(S3, XB, ln1g, ln1b, X1B, 1);

  // cross attention
  gemm_bf16<<<gg, 256, 0, stream>>>(X1B,  WT + 3 * MB, cabq, QH, 2, 0);
  gemm_bf16<<<gg, 256, 0, stream>>>(CTXB, WT + 4 * MB, cabk, KH, 2, 0);
  gemm_bf16<<<gg, 256, 0, stream>>>(CTXB, WT + 5 * MB, cabv, VH, 2, 0);
  attn_mfma<<<ag, 256, 0, stream>>>(QH, KH, VH, MBCA, S3);
  ln_kernel<<<lg, 256, 0, stream>>>(S3, X1B, ln2g, ln2b, X2B, 1);

  // MLP
  gemm_bf16<<<gg, 256, 0, stream>>>(X2B, WT + 6 * MB, b1, QH, 1, 1);  // relu->bf16
  gemm_bf16<<<gg, 256, 0, stream>>>(QH,  WT + 7 * MB, b2, S3, 0, 0);
  ln_kernel<<<lg, 256, 0, stream>>>(S3, X2B, ln3g, ln3b, outp, 0);
}

// Round 3
// 476.980 us; speedup vs baseline: 2.5254x; 1.0127x over previous
//
#include <hip/hip_runtime.h>
#include <math.h>

#define NHEADS 16

typedef __attribute__((ext_vector_type(8))) short bf16x8;
typedef __attribute__((ext_vector_type(4))) float f32x4;

__device__ inline short f2b(float f) {
  unsigned u = __float_as_uint(f);
  u += 0x7fffu + ((u >> 16) & 1u);
  return (short)(u >> 16);
}
__device__ inline float b2f(short s) {
  return __uint_as_float(((unsigned)(unsigned short)s) << 16);
}
__device__ inline void gld16(const void* g, void* l) {
  __builtin_amdgcn_global_load_lds(
      (const __attribute__((address_space(1))) unsigned int*)g,
      (__attribute__((address_space(3))) unsigned int*)l, 16, 0, 0);
}
#define MFMA16(a, b, c) __builtin_amdgcn_mfma_f32_16x16x32_bf16(a, b, c, 0, 0, 0)

// ---------------------------------------------------------------------------
__global__ __launch_bounds__(256) void cvtb(const float* __restrict__ in,
                                            short* __restrict__ out, int n4) {
  int i = blockIdx.x * 256 + threadIdx.x;
  if (i < n4) {
    float4 v = ((const float4*)in)[i];
    short4 s;
    s.x = f2b(v.x); s.y = f2b(v.y); s.z = f2b(v.z); s.w = f2b(v.w);
    ((short4*)out)[i] = s;
  }
}

__global__ __launch_bounds__(256) void maskcomb(const float* __restrict__ a,
                                                const float* __restrict__ b,
                                                short* __restrict__ out, int n4) {
  int i = blockIdx.x * 256 + threadIdx.x;
  if (i < n4) {
    float4 va = ((const float4*)a)[i];
    if (b) {
      float4 vb = ((const float4*)b)[i];
      va.x += vb.x; va.y += vb.y; va.z += vb.z; va.w += vb.w;
    }
    short4 s;
    s.x = f2b(va.x); s.y = f2b(va.y); s.z = f2b(va.z); s.w = f2b(va.w);
    ((short4*)out)[i] = s;
  }
}

// ---------------------------------------------------------------------------
// W fp32 [k][n] -> bf16 [n][k]
// ---------------------------------------------------------------------------
__global__ __launch_bounds__(256) void wtrans(
    const float* W0, const float* W1, const float* W2, const float* W3,
    const float* W4, const float* W5, const float* W6, const float* W7,
    short* __restrict__ out) {
  __shared__ float t[64][65];
  const float* W;
  switch (blockIdx.z) {
    case 0: W = W0; break; case 1: W = W1; break;
    case 2: W = W2; break; case 3: W = W3; break;
    case 4: W = W4; break; case 5: W = W5; break;
    case 6: W = W6; break; default: W = W7; break;
  }
  short* o = out + (size_t)blockIdx.z * 1024 * 1024;
  const int tid = threadIdx.x;
  const int n0 = blockIdx.x * 64, k0 = blockIdx.y * 64;
  const int cg = (tid & 15) * 4, rg = tid >> 4;
  #pragma unroll
  for (int r = 0; r < 4; ++r) {
    int kl = rg + r * 16;
    float4 v = *(const float4*)(W + (size_t)(k0 + kl) * 1024 + n0 + cg);
    t[kl][cg + 0] = v.x; t[kl][cg + 1] = v.y;
    t[kl][cg + 2] = v.z; t[kl][cg + 3] = v.w;
  }
  __syncthreads();
  #pragma unroll
  for (int r = 0; r < 4; ++r) {
    int nl = rg + r * 16;
    short4 s;
    s.x = f2b(t[cg + 0][nl]); s.y = f2b(t[cg + 1][nl]);
    s.z = f2b(t[cg + 2][nl]); s.w = f2b(t[cg + 3][nl]);
    *(short4*)(o + (size_t)(n0 + nl) * 1024 + k0 + cg) = s;
  }
}

__global__ __launch_bounds__(256) void biascat(
    const float* q, const float* k, const float* v,
    const float* ck, const float* cv,
    float* __restrict__ qkvb, float* __restrict__ kvb) {
  int i = blockIdx.x * 256 + threadIdx.x;
  if (i < 1024) qkvb[i] = q[i];
  else if (i < 2048) qkvb[i] = k[i - 1024];
  else if (i < 3072) qkvb[i] = v[i - 2048];
  else if (i < 4096) kvb[i - 3072] = ck[i - 3072];
  else if (i < 5120) kvb[i - 3072] = cv[i - 4096];
}

// ---------------------------------------------------------------------------
// kmax[bh] = max_j |K_row| over head-major KH (bh,1024,64)
// ---------------------------------------------------------------------------
__global__ __launch_bounds__(256) void knorm(const short* __restrict__ kh,
                                             float* __restrict__ kmax) {
  const int bh = blockIdx.x;
  const int tid = threadIdx.x;
  const short* base = kh + (size_t)bh * 65536;
  float mx = 0.f;
  #pragma unroll
  for (int rr = 0; rr < 4; ++rr) {
    int row = tid + rr * 256;
    const bf16x8* rp = (const bf16x8*)(base + (size_t)row * 64);
    float ssq = 0.f;
    #pragma unroll
    for (int c = 0; c < 8; ++c) {
      bf16x8 v = rp[c];
      #pragma unroll
      for (int e = 0; e < 8; ++e) { float f = b2f(v[e]); ssq += f * f; }
    }
    mx = fmaxf(mx, ssq);
  }
  #pragma unroll
  for (int off = 1; off < 64; off <<= 1) mx = fmaxf(mx, __shfl_xor(mx, off, 64));
  __shared__ float wmax[4];
  if ((tid & 63) == 0) wmax[tid >> 6] = mx;
  __syncthreads();
  if (tid == 0)
    kmax[bh] = sqrtf(fmaxf(fmaxf(wmax[0], wmax[1]), fmaxf(wmax[2], wmax[3]))) * 1.0001f;
}

// ---------------------------------------------------------------------------
// GEMM 64x64 tile, BK=64, 2x2 waves (32x32 each), XOR-swizzled LDS.
// modes: 0 fp32 flat; 1 bf16 flat; 2 head-major->C0;
//        3 QKV fused (q->C0 hm, k->C1 hm, v->C2 v-transposed);
//        4 KV fused (k->C1 hm, v->C2 vt)
// ---------------------------------------------------------------------------
__global__ __launch_bounds__(256) void gemm_bf16(
    const short* __restrict__ A, const short* __restrict__ Bt,
    const float* __restrict__ bias,
    void* __restrict__ C0, short* __restrict__ C1, short* __restrict__ C2,
    int mode, int relu) {
  __shared__ short As[64 * 64];
  __shared__ short Bs[64 * 64];
  const int tid = threadIdx.x;
  const int w = tid >> 6, l = tid & 63;
  const int ln = l & 15, lq = l >> 4;
  const int wm = w >> 1, wn = w & 1;
  const int m0 = blockIdx.x * 64, n0 = blockIdx.y * 64;
  const int K = 1024;

  f32x4 acc[2][2];
  #pragma unroll
  for (int s = 0; s < 2; ++s)
    #pragma unroll
    for (int t = 0; t < 2; ++t) acc[s][t] = (f32x4){0.f, 0.f, 0.f, 0.f};

  const int lrow = l >> 3;               // 0..7
  const int lc = (l & 7) ^ lrow;         // swizzled logical k-chunk
  const short* ga = A + (size_t)(m0 + w * 16 + lrow) * K + lc * 8;
  const short* gb = Bt + (size_t)(n0 + w * 16 + lrow) * K + lc * 8;

  const int sw = ln & 7;                 // frag-read swizzle key

  for (int k0 = 0; k0 < K; k0 += 64) {
    __syncthreads();
    gld16(ga + k0, &As[w * 1024]);
    gld16(ga + 8 * K + k0, &As[w * 1024 + 512]);
    gld16(gb + k0, &Bs[w * 1024]);
    gld16(gb + 8 * K + k0, &Bs[w * 1024 + 512]);
    __syncthreads();
    bf16x8 af[2][2], bfr[2][2];
    #pragma unroll
    for (int s = 0; s < 2; ++s) {
      int Rm = wm * 32 + s * 16 + ln;
      int Rn = wn * 32 + s * 16 + ln;
      #pragma unroll
      for (int kc = 0; kc < 2; ++kc) {
        int slot = ((kc * 4 + lq) ^ sw) * 8;
        af[s][kc] = *(const bf16x8*)&As[Rm * 64 + slot];
        bfr[s][kc] = *(const bf16x8*)&Bs[Rn * 64 + slot];
      }
    }
    #pragma unroll
    for (int s = 0; s < 2; ++s)
      #pragma unroll
      for (int t = 0; t < 2; ++t) {
        acc[s][t] = MFMA16(af[s][0], bfr[t][0], acc[s][t]);
        acc[s][t] = MFMA16(af[s][1], bfr[t][1], acc[s][t]);
      }
  }

  float bv[2];
  #pragma unroll
  for (int t = 0; t < 2; ++t) bv[t] = bias[n0 + wn * 32 + t * 16 + ln];

  #pragma unroll
  for (int s = 0; s < 2; ++s) {
    #pragma unroll
    for (int t = 0; t < 2; ++t) {
      #pragma unroll
      for (int r = 0; r < 4; ++r) {
        int m = m0 + wm * 32 + s * 16 + lq * 4 + r;
        int n = n0 + wn * 32 + t * 16 + ln;
        float v = acc[s][t][r] + bv[t];
        if (relu) v = fmaxf(v, 0.f);
        int bb = m >> 10, ii = m & 1023;
        if (mode == 0) {
          ((float*)C0)[(size_t)m * 1024 + n] = v;
        } else if (mode == 1) {
          ((short*)C0)[(size_t)m * 1024 + n] = f2b(v);
        } else if (mode == 2) {
          int d = n >> 4, hh = n & 15;
          ((short*)C0)[(((size_t)(bb * 16 + hh)) * 1024 + ii) * 64 + d] = f2b(v);
        } else if (mode == 3) {
          int sel = n >> 10, nn = n & 1023;
          int d = nn >> 4, hh = nn & 15;
          if (sel == 0)
            ((short*)C0)[(((size_t)(bb * 16 + hh)) * 1024 + ii) * 64 + d] = f2b(v);
          else if (sel == 1)
            C1[(((size_t)(bb * 16 + hh)) * 1024 + ii) * 64 + d] = f2b(v);
          else
            C2[(((size_t)(bb * 16 + hh)) * 64 + d) * 1024 + ii] = f2b(v);
        } else {  // mode 4
          int sel = n >> 10, nn = n & 1023;
          int d = nn >> 4, hh = nn & 15;
          if (sel == 0)
            C1[(((size_t)(bb * 16 + hh)) * 1024 + ii) * 64 + d] = f2b(v);
          else
            C2[(((size_t)(bb * 16 + hh)) * 64 + d) * 1024 + ii] = f2b(v);
        }
      }
    }
  }
}

// ---------------------------------------------------------------------------
// Single-pass flash attention with row-max upper bound M_i = |q_i|*kmax/8.
// out = (sum exp(s-M) V)/l + mask@V.  No barriers in the j-loop.
// q: head-major (bh,1024,64); k: head-major; vt: transposed (bh,64,1024);
// maskb bf16 (b,1024,1024); out fp32 (b,1024,1024) col=(o*16+h).
// grid 512 (swizzled 1-D), 4 waves, wave w owns i-rows [i0+w*16, +16).
// ---------------------------------------------------------------------------
__global__ __launch_bounds__(256) void attn_flash(
    const short* __restrict__ qh, const short* __restrict__ kh,
    const short* __restrict__ vt, const short* __restrict__ maskb,
    const float* __restrict__ kmax, float* __restrict__ out) {
  __shared__ short Ps[4][16 * 72];
  __shared__ float Ml[64];
  const int tid = threadIdx.x;
  const int w = tid >> 6, l = tid & 63;
  const int ln = l & 15, lq = l >> 4;
  const int id = blockIdx.x;
  const int bh = ((id >> 7) << 3) | (id & 7);  // group i-tiles of one (b,h) on one XCD
  const int it = (id >> 3) & 15;
  const int b = bh >> 4, h = bh & 15;
  const int i0 = it * 64;
  const size_t bho = (size_t)bh * 65536;

  // Q fragments (A-operand), rows i0 + w*16 + ln
  const short* qp = qh + bho + (size_t)(i0 + w * 16 + ln) * 64 + lq * 8;
  bf16x8 qf0 = *(const bf16x8*)qp;
  bf16x8 qf1 = *(const bf16x8*)(qp + 32);

  // M_i = |q_i| * kmax / 8  (upper bound on row max of scores)
  float ssq = 0.f;
  #pragma unroll
  for (int e = 0; e < 8; ++e) {
    float f0 = b2f(qf0[e]), f1 = b2f(qf1[e]);
    ssq += f0 * f0 + f1 * f1;
  }
  ssq += __shfl_xor(ssq, 16, 64);
  ssq += __shfl_xor(ssq, 32, 64);
  if (lq == 0) Ml[w * 16 + ln] = sqrtf(ssq) * kmax[bh] * 0.125f + 1e-3f;
  float Mr[4], lac[4];
  #pragma unroll
  for (int r = 0; r < 4; ++r) { Mr[r] = Ml[w * 16 + lq * 4 + r]; lac[r] = 0.f; }

  const short* kbase = kh + bho;
  const short* vbase = vt + bho;
  const short* mbase = maskb + ((size_t)(b * 1024 + i0 + w * 16 + ln)) * 1024;
  short* PsW = &Ps[w][0];

  f32x4 oa[4], mo[4];
  #pragma unroll
  for (int os = 0; os < 4; ++os) {
    oa[os] = (f32x4){0.f, 0.f, 0.f, 0.f};
    mo[os] = (f32x4){0.f, 0.f, 0.f, 0.f};
  }

  for (int jt = 0; jt < 16; ++jt) {
    const short* kt = kbase + (size_t)jt * 4096;
    f32x4 sa[4];
    #pragma unroll
    for (int js = 0; js < 4; ++js) {
      const short* kp = kt + (size_t)(js * 16 + ln) * 64 + lq * 8;
      bf16x8 kb0 = *(const bf16x8*)kp;
      bf16x8 kb1 = *(const bf16x8*)(kp + 32);
      f32x4 s = (f32x4){0.f, 0.f, 0.f, 0.f};
      s = MFMA16(qf0, kb0, s);
      s = MFMA16(qf1, kb1, s);
      sa[js] = s;
    }
    #pragma unroll
    for (int js = 0; js < 4; ++js)
      #pragma unroll
      for (int r = 0; r < 4; ++r) {
        float p = __expf(sa[js][r] * 0.125f - Mr[r]);
        lac[r] += p;
        PsW[(lq * 4 + r) * 72 + js * 16 + ln] = f2b(p);
      }
    bf16x8 pa0 = *(const bf16x8*)&PsW[ln * 72 + lq * 8];
    bf16x8 pa1 = *(const bf16x8*)&PsW[ln * 72 + 32 + lq * 8];
    bf16x8 ma0 = *(const bf16x8*)(mbase + jt * 64 + lq * 8);
    bf16x8 ma1 = *(const bf16x8*)(mbase + jt * 64 + 32 + lq * 8);
    #pragma unroll
    for (int os = 0; os < 4; ++os) {
      const short* vp = vbase + (size_t)(os * 16 + ln) * 1024 + jt * 64 + lq * 8;
      bf16x8 vb0 = *(const bf16x8*)vp;
      bf16x8 vb1 = *(const bf16x8*)(vp + 32);
      oa[os] = MFMA16(pa0, vb0, oa[os]);
      oa[os] = MFMA16(pa1, vb1, oa[os]);
      mo[os] = MFMA16(ma0, vb0, mo[os]);
      mo[os] = MFMA16(ma1, vb1, mo[os]);
    }
  }

  #pragma unroll
  for (int r = 0; r < 4; ++r) {
    #pragma unroll
    for (int off = 1; off < 16; off <<= 1)
      lac[r] += __shfl_xor(lac[r], off, 64);
  }
  float inv[4];
  #pragma unroll
  for (int r = 0; r < 4; ++r) inv[r] = 1.f / lac[r];

  #pragma unroll
  for (int os = 0; os < 4; ++os)
    #pragma unroll
    for (int r = 0; r < 4; ++r) {
      int row = i0 + w * 16 + lq * 4 + r;
      int col = (os * 16 + ln) * NHEADS + h;
      out[((size_t)b * 1024 + row) * 1024 + col] = oa[os][r] * inv[r] + mo[os][r];
    }
}

// ---------------------------------------------------------------------------
__global__ __launch_bounds__(256) void ln_kernel(
    const float* __restrict__ x, const short* __restrict__ res,
    const float* __restrict__ g, const float* __restrict__ be,
    void* __restrict__ outp, int out_bf16) {
  const int row = blockIdx.x;
  const int tid = threadIdx.x;
  float4 v = ((const float4*)(x + (size_t)row * 1024))[tid];
  float s = v.x + v.y + v.z + v.w;
  float sq = v.x * v.x + v.y * v.y + v.z * v.z + v.w * v.w;
  #pragma unroll
  for (int off = 32; off > 0; off >>= 1) {
    s += __shfl_down(s, off, 64);
    sq += __shfl_down(sq, off, 64);
  }
  __shared__ float rs[4], rq[4], stat[2];
  int wave = tid >> 6, lane = tid & 63;
  if (lane == 0) { rs[wave] = s; rq[wave] = sq; }
  __syncthreads();
  if (tid == 0) {
    float S = rs[0] + rs[1] + rs[2] + rs[3];
    float Q = rq[0] + rq[1] + rq[2] + rq[3];
    float mean = S * (1.f / 1024.f);
    float var = Q * (1.f / 1024.f) - mean * mean;
    stat[0] = mean;
    stat[1] = rsqrtf(var + 1e-5f);
  }
  __syncthreads();
  float mean = stat[0], rstd = stat[1];
  float4 g4 = ((const float4*)g)[tid];
  float4 b4 = ((const float4*)be)[tid];
  short4 r4 = ((const short4*)(res + (size_t)row * 1024))[tid];
  float o0 = (v.x - mean) * rstd * g4.x + b4.x + b2f(r4.x);
  float o1 = (v.y - mean) * rstd * g4.y + b4.y + b2f(r4.y);
  float o2 = (v.z - mean) * rstd * g4.z + b4.z + b2f(r4.z);
  float o3 = (v.w - mean) * rstd * g4.w + b4.w + b2f(r4.w);
  if (out_bf16) {
    short4 o;
    o.x = f2b(o0); o.y = f2b(o1); o.z = f2b(o2); o.w = f2b(o3);
    ((short4*)outp)[(size_t)row * 256 + tid] = o;
  } else {
    float4 o = {o0, o1, o2, o3};
    ((float4*)outp)[(size_t)row * 256 + tid] = o;
  }
}

// ---------------------------------------------------------------------------
extern "C" void kernel_launch(void* const* d_in, const int* in_sizes, int n_in,
                              void* d_out, int out_size, void* d_ws, size_t ws_size,
                              hipStream_t stream) {
  const float* x    = (const float*)d_in[0];
  const float* ctx  = (const float*)d_in[1];
  const float* cm   = (const float*)d_in[2];
  const float* ppm  = (const float*)d_in[3];
  const float* cpm  = (const float*)d_in[4];
  const float* saWq = (const float*)d_in[5];
  const float* sabq = (const float*)d_in[6];
  const float* saWk = (const float*)d_in[7];
  const float* sabk = (const float*)d_in[8];
  const float* saWv = (const float*)d_in[9];
  const float* sabv = (const float*)d_in[10];
  const float* caWq = (const float*)d_in[11];
  const float* cabq = (const float*)d_in[12];
  const float* caWk = (const float*)d_in[13];
  const float* cabk = (const float*)d_in[14];
  const float* caWv = (const float*)d_in[15];
  const float* cabv = (const float*)d_in[16];
  const float* ln1g = (const float*)d_in[17];
  const float* ln1b = (const float*)d_in[18];
  const float* ln2g = (const float*)d_in[19];
  const float* ln2b = (const float*)d_in[20];
  const float* ln3g = (const float*)d_in[21];
  const float* ln3b = (const float*)d_in[22];
  const float* W1   = (const float*)d_in[23];
  const float* b1   = (const float*)d_in[24];
  const float* W2   = (const float*)d_in[25];
  const float* b2   = (const float*)d_in[26];

  char* ws = (char*)d_ws;
  const size_t MB = 1024 * 1024;
  short* WT    = (short*)(ws);              // 8 weights x 2MB, [n][k] bf16
  float* qkvb  = (float*)(ws + 16 * MB);
  float* kvb   = (float*)(ws + 16 * MB + 16384);
  float* kmaxb = (float*)(ws + 16 * MB + 32768);
  short* MBSA  = (short*)(ws + 17 * MB);
  short* MBCA  = (short*)(ws + 21 * MB);
  short* XB    = (short*)(ws + 25 * MB);
  short* CTXB  = (short*)(ws + 29 * MB);
  short* QH    = (short*)(ws + 33 * MB);
  short* KH    = (short*)(ws + 37 * MB);
  short* VT    = (short*)(ws + 41 * MB);
  float* S3    = (float*)(ws + 45 * MB);    // 8MB fp32
  short* X1B   = (short*)(ws + 53 * MB);
  short* X2B   = MBSA;                       // dead after self-attn
  short* HB    = CTXB;                       // dead after cross KV gemm
  float* outp  = (float*)d_out;

  const int n4 = 2048 * 1024 / 4;
  dim3 cg(n4 / 256);
  dim3 wg(16, 16, 8);
  dim3 lg(2048);

  // prep (weight order: saWq saWk saWv | caWk caWv | caWq | W1 W2)
  wtrans<<<wg, 256, 0, stream>>>(saWq, saWk, saWv, caWk, caWv, caWq, W1, W2, WT);
  biascat<<<dim3(20), 256, 0, stream>>>(sabq, sabk, sabv, cabk, cabv, qkvb, kvb);
  cvtb<<<cg, 256, 0, stream>>>(x, XB, n4);
  cvtb<<<cg, 256, 0, stream>>>(ctx, CTXB, n4);
  maskcomb<<<cg, 256, 0, stream>>>(cm, ppm, MBSA, n4);
  maskcomb<<<cg, 256, 0, stream>>>(cpm, nullptr, MBCA, n4);

  // ---- self attention ----
  gemm_bf16<<<dim3(32, 48), 256, 0, stream>>>(XB, WT, qkvb, QH, KH, VT, 3, 0);
  knorm<<<dim3(32), 256, 0, stream>>>(KH, kmaxb);
  attn_flash<<<dim3(512), 256, 0, stream>>>(QH, KH, VT, MBSA, kmaxb, S3);
  ln_kernel<<<lg, 256, 0, stream>>>(S3, XB, ln1g, ln1b, X1B, 1);

  // ---- cross attention ----
  gemm_bf16<<<dim3(32, 16), 256, 0, stream>>>(X1B, WT + 5 * 1048576, cabq,
                                              QH, nullptr, nullptr, 2, 0);
  gemm_bf16<<<dim3(32, 32), 256, 0, stream>>>(CTXB, WT + 3 * 1048576, kvb,
                                              nullptr, KH, VT, 4, 0);
  knorm<<<dim3(32), 256, 0, stream>>>(KH, kmaxb);
  attn_flash<<<dim3(512), 256, 0, stream>>>(QH, KH, VT, MBCA, kmaxb, S3);
  ln_kernel<<<lg, 256, 0, stream>>>(S3, X1B, ln2g, ln2b, X2B, 1);

  // ---- MLP ----
  gemm_bf16<<<dim3(32, 16), 256, 0, stream>>>(X2B, WT + 6 * 1048576, b1,
                                              HB, nullptr, nullptr, 1, 1);
  gemm_bf16<<<dim3(32, 16), 256, 0, stream>>>(HB, WT + 7 * 1048576, b2,
                                              S3, nullptr, nullptr, 0, 0);
  ln_kernel<<<lg, 256, 0, stream>>>(S3, X2B, ln3g, ln3b, outp, 0);
}